// Round 13
// baseline (2189.757 us; speedup 1.0000x reference)
//
#include <hip/hip_runtime.h>
#include <hip/hip_bf16.h>
#include <cstdint>
#include <cstddef>

#define NPTS   4096
#define NPT    1024            // NPOINT (S)
#define NSAMP  32
#define NBATCH 16
#define MROWS  (NBATCH*NPT*NSAMP)   // 524288 rows for the conv layers
#define EPSV   1e-5f

typedef __attribute__((ext_vector_type(8))) short bfrag;   // 8 bf16 = 4 VGPRs
typedef __attribute__((ext_vector_type(4))) float f32x4;

static __device__ __forceinline__ unsigned short f2bf(float f) {
  union { float f; unsigned u; } x; x.f = f;
  unsigned u = x.u;
  u += 0x7FFFu + ((u >> 16) & 1u);
  return (unsigned short)(u >> 16);
}
static __device__ __forceinline__ float bf2f(unsigned short h) {
  union { unsigned u; float f; } x; x.u = ((unsigned)h) << 16;
  return x.f;
}
static __device__ __forceinline__ unsigned cvt_pk_bf16(float lo, float hi) {
  unsigned r;
  asm("v_cvt_pk_bf16_f32 %0, %1, %2" : "=v"(r) : "v"(lo), "v"(hi));
  return r;
}

// ---------------------------------------------------------------------------
// Kernel 0: prep (merged). Block 0 converts weights (W0 channel-permuted to
// [pf64 | relxyz3 | 0*29]); all blocks grid-stride convert points -> bf16
// (same RNE rounding the gather used before — numerically identical product).
// ---------------------------------------------------------------------------
__global__ __launch_bounds__(256) void prep_kernel(
    const float* __restrict__ w0, const float* __restrict__ w1,
    const float* __restrict__ w2, unsigned short* __restrict__ wb0,
    unsigned short* __restrict__ wb1, unsigned short* __restrict__ wb2,
    const float* __restrict__ points, unsigned short* __restrict__ pointsb) {
  const int tid = threadIdx.x;
  if (blockIdx.x == 0) {
    for (int i = tid; i < 64 * 96; i += 256) {
      const int o = i / 96, c = i % 96;
      float v;
      if (c < 64)      v = w0[o * 67 + 3 + c];
      else if (c < 67) v = w0[o * 67 + (c - 64)];
      else             v = 0.f;
      wb0[i] = f2bf(v);
    }
    for (int i = tid; i < 64 * 64; i += 256) wb1[i] = f2bf(w1[i]);
    for (int i = tid; i < 128 * 64; i += 256) wb2[i] = f2bf(w2[i]);
  }
  const int n2 = NBATCH * NPTS * 64 / 2;   // 2 floats -> 1 packed u32
  for (int i = blockIdx.x * 256 + tid; i < n2; i += gridDim.x * 256) {
    const float2 v = ((const float2*)points)[i];
    ((unsigned*)pointsb)[i] = cvt_pk_bf16(v.x, v.y);
  }
}

// ---------------------------------------------------------------------------
// Kernel 1: farthest point sampling, v7 = r6 structure with the in-thread
// SERIAL argmax scan replaced by a DEPTH-4 TREE (same instruction count,
// dependency depth 4 instead of 16; the 16 distance updates become fully
// independent -> better ILP). Tie-break exact: strict-> keep-left at every
// level == lowest index == numpy first-max. Distance math unchanged
// (__f*_rn, (dx^2+dy^2)+dz^2). Everything else byte-identical to r6.
// ---------------------------------------------------------------------------
#define FPS_T 256
#define PPT   (NPTS / FPS_T)   // 16

template <int CTRL>
static __device__ __forceinline__ float dpp_max_step(float v) {
  int t = __builtin_amdgcn_update_dpp(0, __float_as_int(v), CTRL, 0xF, 0xF, true);
  return fmaxf(v, __int_as_float(t));
}

__global__ __launch_bounds__(FPS_T) void fps_kernel(
    const float* __restrict__ xyz, float* __restrict__ out_newxyz) {
  __shared__ __align__(16) float xs[NPTS];
  __shared__ __align__(16) float ys[NPTS];
  __shared__ __align__(16) float zs[NPTS];
  __shared__ __align__(16) float olds[NPT * 3];
  __shared__ __align__(16) uint2 sl[2][4];   // (bits(max), idx) per wave

  const int b = blockIdx.x;
  const int tid = threadIdx.x;
  const int wave = tid >> 6;
  const float* base = xyz + (size_t)b * NPTS * 3;
  for (int i = tid; i < NPTS; i += FPS_T) {
    xs[i] = base[3 * i + 0];
    ys[i] = base[3 * i + 1];
    zs[i] = base[3 * i + 2];
  }
  __syncthreads();

  const int p0 = tid * PPT;
  float px[PPT], py[PPT], pz[PPT], dist[PPT];
  #pragma unroll
  for (int i = 0; i < PPT; i += 4) {
    *(float4*)&px[i] = *(const float4*)&xs[p0 + i];
    *(float4*)&py[i] = *(const float4*)&ys[p0 + i];
    *(float4*)&pz[i] = *(const float4*)&zs[p0 + i];
  }
  #pragma unroll
  for (int i = 0; i < PPT; ++i) dist[i] = 1e10f;

  int cur = 0;
  for (int it = 0; it < NPT; ++it) {
    const float cx = xs[cur], cy = ys[cur], cz = zs[cur];
    if (tid == 0) {
      olds[3 * it + 0] = cx;
      olds[3 * it + 1] = cy;
      olds[3 * it + 2] = cz;
    }
    if (it == NPT - 1) break;

    // independent distance updates (no serial chain)
    float tv[PPT]; int ti[PPT];
    #pragma unroll
    for (int i = 0; i < PPT; ++i) {
      const float dx = __fsub_rn(px[i], cx);
      const float dy = __fsub_rn(py[i], cy);
      const float dz = __fsub_rn(pz[i], cz);
      const float d = __fadd_rn(__fadd_rn(__fmul_rn(dx, dx), __fmul_rn(dy, dy)),
                                __fmul_rn(dz, dz));
      const float nd = fminf(dist[i], d);
      dist[i] = nd;
      tv[i] = nd;
      ti[i] = p0 + i;
    }
    // depth-4 tree argmax; strict > keeps LEFT on ties -> lowest index
    #pragma unroll
    for (int st = PPT / 2; st >= 1; st >>= 1) {
      #pragma unroll
      for (int i = 0; i < st; ++i) {
        const bool g = tv[i + st] > tv[i];
        tv[i] = g ? tv[i + st] : tv[i];
        ti[i] = g ? ti[i + st] : ti[i];
      }
    }
    const float bestv = tv[0];
    const int besti = ti[0];

    // wave-wide max VALUE (distances >= 0, bound_ctrl zero-fill safe)
    float m = bestv;
    m = dpp_max_step<0x111>(m);   // row_shr:1
    m = dpp_max_step<0x112>(m);   // row_shr:2
    m = dpp_max_step<0x114>(m);   // row_shr:4
    m = dpp_max_step<0x118>(m);   // row_shr:8
    m = dpp_max_step<0x142>(m);   // row_bcast:15
    m = dpp_max_step<0x143>(m);   // row_bcast:31  -> lane 63 holds wave max
    const float wmax =
        __int_as_float(__builtin_amdgcn_readlane(__float_as_int(m), 63));

    // lowest lane matching wave max == lowest index in wave
    const unsigned long long mask = __ballot(bestv == wmax);
    const int wl = __ffsll((long long)mask) - 1;
    const int widx = __builtin_amdgcn_readlane(besti, wl);

    const int buf = it & 1;
    if ((tid & 63) == 0)
      sl[buf][wave] = make_uint2(__float_as_uint(wmax), (unsigned)widx);
    __syncthreads();   // single barrier; double-buffered slots prevent WAR

    // all threads combine the 4 wave winners (2x ds_read_b128 broadcast)
    const uint4* p4 = (const uint4*)&sl[buf][0];
    const uint4 q0 = p4[0], q1 = p4[1];
    float bv; int bi;
    {
      bv = __uint_as_float(q0.x); bi = (int)q0.y;
      const float v1 = __uint_as_float(q0.z);
      if (v1 > bv) { bv = v1; bi = (int)q0.w; }
      const float v2 = __uint_as_float(q1.x);
      if (v2 > bv) { bv = v2; bi = (int)q1.y; }
      const float v3 = __uint_as_float(q1.z);
      if (v3 > bv) { bv = v3; bi = (int)q1.w; }
    }
    cur = bi;
  }

  __syncthreads();
  float* outb = out_newxyz + (size_t)b * NPT * 3;
  for (int i = tid; i < NPT * 3 / 4; i += FPS_T)
    *(float4*)&outb[4 * i] = *(const float4*)&olds[4 * i];
}

// ---------------------------------------------------------------------------
// Kernel 3: layer-1 MFMA matmul with fused ball query (unchanged from r12).
// ---------------------------------------------------------------------------
__global__ __launch_bounds__(256) void mm1_mfma_kernel(
    const float* __restrict__ xyz, const unsigned short* __restrict__ pointsb,
    const float* __restrict__ newxyz, const unsigned short* __restrict__ Wb,
    unsigned short* __restrict__ Y, float* __restrict__ psum,
    float* __restrict__ psq) {
  constexpr int KP = 104;
  __shared__ __align__(16) unsigned short As[64 * KP];
  __shared__ __align__(16) unsigned short ly[64 * 64];
  __shared__ float ssum[64], ssq[64];
  __shared__ int   gidxL[64];
  __shared__ float cents[8];
  const int tid = threadIdx.x, bid = blockIdx.x;
  const int wave = tid >> 6, lane = tid & 63;
  const size_t r0 = (size_t)bid * 64;
  const int b = (bid * 2) >> 10;

  // ---- fused ball query: wave w in {0,1} handles group bid*2+w ----
  if (wave < 2) {
    const int gs = bid * 2 + wave;
    const float* base = xyz + (size_t)b * NPTS * 3;
    const float* c = newxyz + (size_t)gs * 3;
    const float cx = c[0], cy = c[1], cz = c[2];
    if (lane == 0) {
      cents[wave * 4 + 0] = cx;
      cents[wave * 4 + 1] = cy;
      cents[wave * 4 + 2] = cz;
    }
    const float R2 = (float)(0.2 * 0.2);
    int* g = &gidxL[wave * 32];
    int count = 0;
    int first = -1;
    for (int ch = 0; ch < NPTS / 64; ++ch) {
      const int i = ch * 64 + lane;
      const float dx = __fsub_rn(base[3 * i + 0], cx);
      const float dy = __fsub_rn(base[3 * i + 1], cy);
      const float dz = __fsub_rn(base[3 * i + 2], cz);
      const float d = __fadd_rn(
          __fadd_rn(__fmul_rn(dx, dx), __fmul_rn(dy, dy)), __fmul_rn(dz, dz));
      const bool pred = !(d > R2);
      const unsigned long long mask = __ballot(pred);
      if (mask) {
        if (count == 0) first = ch * 64 + (__ffsll((long long)mask) - 1);
        const int rank = __popcll(mask & ((1ull << lane) - 1ull));
        const int pos = count + rank;
        if (pred && pos < NSAMP) g[pos] = i;
        count += (int)__popcll(mask);
        if (count >= NSAMP) break;
      }
    }
    if (first < 0) first = 0;
    for (int j = count + lane; j < NSAMP; j += 64) g[j] = first;
  }
  if (tid < 64) { ssum[tid] = 0.f; ssq[tid] = 0.f; }
  __syncthreads();

  // ---- gather: 4 threads/row, 16 bf16 channels each (2x uint4 loads) ----
  {
    const int row = tid >> 2, q = tid & 3;
    const int gpt = gidxL[row];
    const unsigned short* pf = pointsb + ((size_t)b * NPTS + gpt) * 64 + 16 * q;
    const uint4 u0 = *(const uint4*)pf;
    const uint4 u1 = *(const uint4*)(pf + 8);
    uint4* dst = (uint4*)&As[row * KP + 16 * q];
    dst[0] = u0; dst[1] = u1;
    if (q == 0) {
      const float* px = xyz + ((size_t)b * NPTS + gpt) * 3;
      const float* pc = &cents[(row >> 5) * 4];
      const float rx = px[0] - pc[0];
      const float ry = px[1] - pc[1];
      const float rz = px[2] - pc[2];
      uint4* d2 = (uint4*)&As[row * KP + 64];
      d2[0] = uint4{cvt_pk_bf16(rx, ry), cvt_pk_bf16(rz, 0.f), 0u, 0u};
      d2[1] = uint4{0u, 0u, 0u, 0u};
      d2[2] = uint4{0u, 0u, 0u, 0u};
      d2[3] = uint4{0u, 0u, 0u, 0u};
    }
  }
  __syncthreads();

  const int l15 = lane & 15, kq = lane >> 4;
  const unsigned short* abase = &As[(wave * 16 + l15) * KP + kq * 8];
  const bfrag a0 = *(const bfrag*)abase;
  const bfrag a1 = *(const bfrag*)(abase + 32);
  const bfrag a2 = *(const bfrag*)(abase + 64);

  #pragma unroll
  for (int nt = 0; nt < 4; ++nt) {
    const unsigned short* wsrc = Wb + (size_t)(nt * 16 + l15) * 96 + kq * 8;
    const bfrag b0 = *(const bfrag*)wsrc;
    const bfrag b1 = *(const bfrag*)(wsrc + 32);
    const bfrag b2 = *(const bfrag*)(wsrc + 64);
    f32x4 acc = {0.f, 0.f, 0.f, 0.f};
    acc = __builtin_amdgcn_mfma_f32_16x16x32_bf16(a0, b0, acc, 0, 0, 0);
    acc = __builtin_amdgcn_mfma_f32_16x16x32_bf16(a1, b1, acc, 0, 0, 0);
    acc = __builtin_amdgcn_mfma_f32_16x16x32_bf16(a2, b2, acc, 0, 0, 0);

    float s = acc[0] + acc[1] + acc[2] + acc[3];
    float q = acc[0]*acc[0] + acc[1]*acc[1] + acc[2]*acc[2] + acc[3]*acc[3];
    s += __shfl_xor(s, 16); q += __shfl_xor(q, 16);
    s += __shfl_xor(s, 32); q += __shfl_xor(q, 32);
    if (kq == 0) {
      atomicAdd(&ssum[nt * 16 + l15], s);
      atomicAdd(&ssq [nt * 16 + l15], q);
    }
    const unsigned p01 = cvt_pk_bf16(acc[0], acc[1]);
    const unsigned p23 = cvt_pk_bf16(acc[2], acc[3]);
    const int colo = nt * 16 + l15;
    const int rbase = wave * 16 + kq * 4;
    ly[(rbase + 0) * 64 + colo] = (unsigned short)(p01 & 0xffffu);
    ly[(rbase + 1) * 64 + colo] = (unsigned short)(p01 >> 16);
    ly[(rbase + 2) * 64 + colo] = (unsigned short)(p23 & 0xffffu);
    ly[(rbase + 3) * 64 + colo] = (unsigned short)(p23 >> 16);
  }
  __syncthreads();
  {
    const uint4* lsrc = (const uint4*)ly;
    uint4* gdst = (uint4*)(Y + r0 * 64);
    #pragma unroll
    for (int i = tid; i < 64 * 64 * 2 / 16; i += 256) gdst[i] = lsrc[i];
  }
  if (tid < 64) {
    psum[(size_t)bid * 64 + tid] = ssum[tid];
    psq [(size_t)bid * 64 + tid] = ssq [tid];
  }
}

// ---------------------------------------------------------------------------
// Layer 2 MFMA (unchanged).
// ---------------------------------------------------------------------------
static __device__ __forceinline__ bfrag affine_relu_frag(
    const unsigned short* __restrict__ src, const float* __restrict__ st,
    int c0) {
  union { bfrag f; unsigned u[4]; } r;
  const uint4 raw = *(const uint4*)src;
  const unsigned w[4] = {raw.x, raw.y, raw.z, raw.w};
  #pragma unroll
  for (int p = 0; p < 4; ++p) {
    const int c = c0 + 2 * p;
    float lo = bf2f((unsigned short)(w[p] & 0xffffu));
    float hi = bf2f((unsigned short)(w[p] >> 16));
    lo = fmaxf(fmaf(lo, st[2 * c + 0], st[2 * c + 1]), 0.f);
    hi = fmaxf(fmaf(hi, st[2 * c + 2], st[2 * c + 3]), 0.f);
    r.u[p] = cvt_pk_bf16(lo, hi);
  }
  return r.f;
}

template <int COUT, int WAVES>
__global__ __launch_bounds__(WAVES * 64) void mm_mfma_kernel(
    const unsigned short* __restrict__ Xin, const unsigned short* __restrict__ Wb,
    const float* __restrict__ stin, unsigned short* __restrict__ Y,
    float* __restrict__ psum, float* __restrict__ psq) {
  constexpr int NT = COUT / 16;
  constexpr int ROWS = WAVES * 16;
  __shared__ float ssum[COUT], ssq[COUT];
  __shared__ __align__(16) unsigned short ly[ROWS * COUT];
  const int tid = threadIdx.x, bid = blockIdx.x;
  const int wave = tid >> 6, lane = tid & 63;
  const int l15 = lane & 15, kq = lane >> 4;
  const size_t r0 = (size_t)bid * ROWS;
  if (tid < COUT) { ssum[tid] = 0.f; ssq[tid] = 0.f; }

  const int arow = wave * 16 + l15;
  const unsigned short* asrc = Xin + (r0 + arow) * 64 + kq * 8;
  const bfrag a0 = affine_relu_frag(asrc, stin, kq * 8);
  const bfrag a1 = affine_relu_frag(asrc + 32, stin, 32 + kq * 8);
  __syncthreads();

  #pragma unroll
  for (int nt = 0; nt < NT; ++nt) {
    const unsigned short* wsrc = Wb + (size_t)(nt * 16 + l15) * 64 + kq * 8;
    const bfrag b0 = *(const bfrag*)wsrc;
    const bfrag b1 = *(const bfrag*)(wsrc + 32);
    f32x4 acc = {0.f, 0.f, 0.f, 0.f};
    acc = __builtin_amdgcn_mfma_f32_16x16x32_bf16(a0, b0, acc, 0, 0, 0);
    acc = __builtin_amdgcn_mfma_f32_16x16x32_bf16(a1, b1, acc, 0, 0, 0);

    float s = acc[0] + acc[1] + acc[2] + acc[3];
    float q = acc[0]*acc[0] + acc[1]*acc[1] + acc[2]*acc[2] + acc[3]*acc[3];
    s += __shfl_xor(s, 16); q += __shfl_xor(q, 16);
    s += __shfl_xor(s, 32); q += __shfl_xor(q, 32);
    if (kq == 0) {
      atomicAdd(&ssum[nt * 16 + l15], s);
      atomicAdd(&ssq [nt * 16 + l15], q);
    }
    const unsigned p01 = cvt_pk_bf16(acc[0], acc[1]);
    const unsigned p23 = cvt_pk_bf16(acc[2], acc[3]);
    const int colo = nt * 16 + l15;
    const int rbase = wave * 16 + kq * 4;
    ly[(rbase + 0) * COUT + colo] = (unsigned short)(p01 & 0xffffu);
    ly[(rbase + 1) * COUT + colo] = (unsigned short)(p01 >> 16);
    ly[(rbase + 2) * COUT + colo] = (unsigned short)(p23 & 0xffffu);
    ly[(rbase + 3) * COUT + colo] = (unsigned short)(p23 >> 16);
  }
  __syncthreads();
  {
    const uint4* lsrc = (const uint4*)ly;
    uint4* gdst = (uint4*)(Y + r0 * COUT);
    #pragma unroll
    for (int i = tid; i < ROWS * COUT * 2 / 16; i += WAVES * 64) gdst[i] = lsrc[i];
  }
  if (tid < COUT) {
    psum[(size_t)bid * COUT + tid] = ssum[tid];
    psq [(size_t)bid * COUT + tid] = ssq [tid];
  }
}

// ---------------------------------------------------------------------------
// Layer 3 MFMA + fused maxpool (unchanged).
// ---------------------------------------------------------------------------
__global__ __launch_bounds__(512) void mm3_pool_kernel(
    const unsigned short* __restrict__ Xin, const unsigned short* __restrict__ Wb,
    const float* __restrict__ stin, float* __restrict__ pooled,
    float* __restrict__ psum, float* __restrict__ psq) {
  constexpr int COUT = 128, NT = 8;
  __shared__ float ssum[COUT], ssq[COUT];
  __shared__ float pm[8][COUT];
  const int tid = threadIdx.x, bid = blockIdx.x;
  const int wave = tid >> 6, lane = tid & 63;
  const int l15 = lane & 15, kq = lane >> 4;
  const size_t r0 = (size_t)bid * 128;
  if (tid < COUT) { ssum[tid] = 0.f; ssq[tid] = 0.f; }

  const int arow = wave * 16 + l15;
  const unsigned short* asrc = Xin + (r0 + arow) * 64 + kq * 8;
  const bfrag a0 = affine_relu_frag(asrc, stin, kq * 8);
  const bfrag a1 = affine_relu_frag(asrc + 32, stin, 32 + kq * 8);
  __syncthreads();

  #pragma unroll
  for (int nt = 0; nt < NT; ++nt) {
    const unsigned short* wsrc = Wb + (size_t)(nt * 16 + l15) * 64 + kq * 8;
    const bfrag b0 = *(const bfrag*)wsrc;
    const bfrag b1 = *(const bfrag*)(wsrc + 32);
    f32x4 acc = {0.f, 0.f, 0.f, 0.f};
    acc = __builtin_amdgcn_mfma_f32_16x16x32_bf16(a0, b0, acc, 0, 0, 0);
    acc = __builtin_amdgcn_mfma_f32_16x16x32_bf16(a1, b1, acc, 0, 0, 0);

    float s = acc[0] + acc[1] + acc[2] + acc[3];
    float q = acc[0]*acc[0] + acc[1]*acc[1] + acc[2]*acc[2] + acc[3]*acc[3];
    s += __shfl_xor(s, 16); q += __shfl_xor(q, 16);
    s += __shfl_xor(s, 32); q += __shfl_xor(q, 32);
    float mx = fmaxf(fmaxf(acc[0], acc[1]), fmaxf(acc[2], acc[3]));
    mx = fmaxf(mx, __shfl_xor(mx, 16));
    mx = fmaxf(mx, __shfl_xor(mx, 32));
    if (kq == 0) {
      atomicAdd(&ssum[nt * 16 + l15], s);
      atomicAdd(&ssq [nt * 16 + l15], q);
      pm[wave][nt * 16 + l15] = mx;
    }
  }
  __syncthreads();
  {
    const int g = tid >> 7, col = tid & 127;
    const float v = fmaxf(pm[2 * g][col], pm[2 * g + 1][col]);
    pooled[(r0 >> 5) * COUT + g * COUT + col] = v;
  }
  if (tid < COUT) {
    psum[(size_t)bid * COUT + tid] = ssum[tid];
    psq [(size_t)bid * COUT + tid] = ssq [tid];
  }
}

// ---------------------------------------------------------------------------
// BN stats finalize (unchanged).
// ---------------------------------------------------------------------------
__global__ __launch_bounds__(256) void finalize_kernel(
    const float* __restrict__ psum, const float* __restrict__ psq,
    const float* __restrict__ gam, const float* __restrict__ bet,
    float* __restrict__ st, int C, int nb) {
  const int c = blockIdx.x, tid = threadIdx.x;
  float s = 0.f, q = 0.f;
  for (int i = tid; i < nb; i += 256) {
    s += psum[(size_t)i * C + c];
    q += psq [(size_t)i * C + c];
  }
  #pragma unroll
  for (int off = 32; off > 0; off >>= 1) {
    s += __shfl_down(s, off);
    q += __shfl_down(q, off);
  }
  __shared__ float as_[4], aq_[4];
  if ((tid & 63) == 0) { as_[tid >> 6] = s; aq_[tid >> 6] = q; }
  __syncthreads();
  if (tid == 0) {
    s = as_[0] + as_[1] + as_[2] + as_[3];
    q = aq_[0] + aq_[1] + aq_[2] + aq_[3];
    const float invM = 1.f / (float)MROWS;
    const float mean = s * invM;
    const float var = q * invM - mean * mean;
    const float inv = 1.f / sqrtf(var + EPSV);
    const float sc = gam[c] * inv;
    st[2 * c + 0] = sc;
    st[2 * c + 1] = bet[c] - mean * sc;
  }
}

// ---------------------------------------------------------------------------
// Epilogue: BN3 affine + relu on the pooled tensor -> new_points.
// ---------------------------------------------------------------------------
__global__ __launch_bounds__(256) void bn_relu_kernel(
    const float* __restrict__ pooled, const float* __restrict__ st,
    float* __restrict__ out) {
  __shared__ float s_st[256];
  const int tid = threadIdx.x;
  s_st[tid] = st[tid];
  __syncthreads();
  const int n4 = NBATCH * NPT * 128 / 4;
  for (int i = blockIdx.x * 256 + tid; i < n4; i += gridDim.x * 256) {
    float4 v = ((const float4*)pooled)[i];
    const int c0 = (i * 4) & 127;
    v.x = fmaxf(fmaf(v.x, s_st[2 * c0 + 0], s_st[2 * c0 + 1]), 0.f);
    v.y = fmaxf(fmaf(v.y, s_st[2 * c0 + 2], s_st[2 * c0 + 3]), 0.f);
    v.z = fmaxf(fmaf(v.z, s_st[2 * c0 + 4], s_st[2 * c0 + 5]), 0.f);
    v.w = fmaxf(fmaf(v.w, s_st[2 * c0 + 6], s_st[2 * c0 + 7]), 0.f);
    ((float4*)out)[i] = v;
  }
}

// ---------------------------------------------------------------------------
extern "C" void kernel_launch(void* const* d_in, const int* in_sizes, int n_in,
                              void* d_out, int out_size, void* d_ws, size_t ws_size,
                              hipStream_t stream) {
  (void)in_sizes; (void)n_in; (void)out_size; (void)ws_size;
  const float* xyz    = (const float*)d_in[0];
  const float* points = (const float*)d_in[1];
  const float* w0 = (const float*)d_in[2];
  const float* g0 = (const float*)d_in[4];
  const float* be0 = (const float*)d_in[5];
  const float* w1 = (const float*)d_in[6];
  const float* g1 = (const float*)d_in[8];
  const float* be1 = (const float*)d_in[9];
  const float* w2 = (const float*)d_in[10];
  const float* g2 = (const float*)d_in[12];
  const float* be2 = (const float*)d_in[13];

  float* out = (float*)d_out;
  float* newxyz = out;
  float* newpts = out + (size_t)NBATCH * NPT * 3;

  char* ws = (char*)d_ws;
  // [0,67MB)      Y1 (dead after mm2) / P3 pooled 8MB (written by mm3 later)
  // [67,75.4MB)   pointsb (bf16 points, 8.4MB)
  // [134,201MB)   Y2
  unsigned short* Y1 = (unsigned short*)ws;
  float* P3 = (float*)ws;
  unsigned short* pointsb = (unsigned short*)(ws + 67108864);
  unsigned short* Y2 = (unsigned short*)(ws + 134217728);
  float* psum = (float*)(ws + 203423744);
  float* psq  = (float*)(ws + 205520896);
  float* st   = (float*)(ws + 207618048);
  float* st1 = st, *st2 = st + 256, *st3 = st + 512;
  unsigned short* wb0 = (unsigned short*)(ws + 207621120);
  unsigned short* wb1 = (unsigned short*)(ws + 207621120 + 12288);
  unsigned short* wb2 = (unsigned short*)(ws + 207621120 + 12288 + 8192);

  prep_kernel<<<512, 256, 0, stream>>>(w0, w1, w2, wb0, wb1, wb2, points, pointsb);
  fps_kernel<<<NBATCH, FPS_T, 0, stream>>>(xyz, newxyz);
  mm1_mfma_kernel<<<MROWS / 64, 256, 0, stream>>>(xyz, pointsb, newxyz, wb0, Y1, psum, psq);
  finalize_kernel<<<64, 256, 0, stream>>>(psum, psq, g0, be0, st1, 64, MROWS / 64);
  mm_mfma_kernel<64, 4><<<MROWS / 64, 256, 0, stream>>>(Y1, wb1, st1, Y2, psum, psq);
  finalize_kernel<<<64, 256, 0, stream>>>(psum, psq, g1, be1, st2, 64, MROWS / 64);
  mm3_pool_kernel<<<MROWS / 128, 512, 0, stream>>>(Y2, wb2, st2, P3, psum, psq);
  finalize_kernel<<<128, 256, 0, stream>>>(psum, psq, g2, be2, st3, 128, MROWS / 128);
  bn_relu_kernel<<<2048, 256, 0, stream>>>(P3, st3, newpts);
}

// Round 14
// 853.558 us; speedup vs baseline: 2.5654x; 2.5654x over previous
//
#include <hip/hip_runtime.h>
#include <hip/hip_bf16.h>
#include <cstdint>
#include <cstddef>

#define NPTS   4096
#define NPT    1024            // NPOINT (S)
#define NSAMP  32
#define NBATCH 16
#define MROWS  (NBATCH*NPT*NSAMP)   // 524288 rows for the conv layers
#define EPSV   1e-5f

typedef __attribute__((ext_vector_type(8))) short bfrag;   // 8 bf16 = 4 VGPRs
typedef __attribute__((ext_vector_type(4))) float f32x4;

static __device__ __forceinline__ unsigned short f2bf(float f) {
  union { float f; unsigned u; } x; x.f = f;
  unsigned u = x.u;
  u += 0x7FFFu + ((u >> 16) & 1u);
  return (unsigned short)(u >> 16);
}
static __device__ __forceinline__ float bf2f(unsigned short h) {
  union { unsigned u; float f; } x; x.u = ((unsigned)h) << 16;
  return x.f;
}
static __device__ __forceinline__ unsigned cvt_pk_bf16(float lo, float hi) {
  unsigned r;
  asm("v_cvt_pk_bf16_f32 %0, %1, %2" : "=v"(r) : "v"(lo), "v"(hi));
  return r;
}

// ---------------------------------------------------------------------------
// Kernel 0: prep (merged). Block 0 converts weights (W0 channel-permuted to
// [pf64 | relxyz3 | 0*29]); all blocks grid-stride convert points -> bf16.
// ---------------------------------------------------------------------------
__global__ __launch_bounds__(256) void prep_kernel(
    const float* __restrict__ w0, const float* __restrict__ w1,
    const float* __restrict__ w2, unsigned short* __restrict__ wb0,
    unsigned short* __restrict__ wb1, unsigned short* __restrict__ wb2,
    const float* __restrict__ points, unsigned short* __restrict__ pointsb) {
  const int tid = threadIdx.x;
  if (blockIdx.x == 0) {
    for (int i = tid; i < 64 * 96; i += 256) {
      const int o = i / 96, c = i % 96;
      float v;
      if (c < 64)      v = w0[o * 67 + 3 + c];
      else if (c < 67) v = w0[o * 67 + (c - 64)];
      else             v = 0.f;
      wb0[i] = f2bf(v);
    }
    for (int i = tid; i < 64 * 64; i += 256) wb1[i] = f2bf(w1[i]);
    for (int i = tid; i < 128 * 64; i += 256) wb2[i] = f2bf(w2[i]);
  }
  const int n2 = NBATCH * NPTS * 64 / 2;   // 2 floats -> 1 packed u32
  for (int i = blockIdx.x * 256 + tid; i < n2; i += gridDim.x * 256) {
    const float2 v = ((const float2*)points)[i];
    ((unsigned*)pointsb)[i] = cvt_pk_bf16(v.x, v.y);
  }
}

// ---------------------------------------------------------------------------
// Kernel 1: farthest point sampling — r6-EXACT (best measured: 569us; DO NOT
// TOUCH). Serial in-thread scan keeps live state minimal (r13's tree argmax
// spilled to scratch: 3.3x regression). 256 threads (4 waves), 16 pts/thread
// in registers, DPP wave-max, exact ballot tie-break, double-buffered slots,
// ONE barrier/iter, LDS-staged centroid output.
// ---------------------------------------------------------------------------
#define FPS_T 256
#define PPT   (NPTS / FPS_T)   // 16

template <int CTRL>
static __device__ __forceinline__ float dpp_max_step(float v) {
  int t = __builtin_amdgcn_update_dpp(0, __float_as_int(v), CTRL, 0xF, 0xF, true);
  return fmaxf(v, __int_as_float(t));
}

__global__ __launch_bounds__(FPS_T) void fps_kernel(
    const float* __restrict__ xyz, float* __restrict__ out_newxyz) {
  __shared__ __align__(16) float xs[NPTS];
  __shared__ __align__(16) float ys[NPTS];
  __shared__ __align__(16) float zs[NPTS];
  __shared__ __align__(16) float olds[NPT * 3];
  __shared__ __align__(16) uint2 sl[2][4];   // (bits(max), idx) per wave

  const int b = blockIdx.x;
  const int tid = threadIdx.x;
  const int wave = tid >> 6;
  const float* base = xyz + (size_t)b * NPTS * 3;
  for (int i = tid; i < NPTS; i += FPS_T) {
    xs[i] = base[3 * i + 0];
    ys[i] = base[3 * i + 1];
    zs[i] = base[3 * i + 2];
  }
  __syncthreads();

  const int p0 = tid * PPT;
  float px[PPT], py[PPT], pz[PPT], dist[PPT];
  #pragma unroll
  for (int i = 0; i < PPT; i += 4) {
    *(float4*)&px[i] = *(const float4*)&xs[p0 + i];
    *(float4*)&py[i] = *(const float4*)&ys[p0 + i];
    *(float4*)&pz[i] = *(const float4*)&zs[p0 + i];
  }
  #pragma unroll
  for (int i = 0; i < PPT; ++i) dist[i] = 1e10f;

  int cur = 0;
  for (int it = 0; it < NPT; ++it) {
    const float cx = xs[cur], cy = ys[cur], cz = zs[cur];
    if (tid == 0) {
      olds[3 * it + 0] = cx;
      olds[3 * it + 1] = cy;
      olds[3 * it + 2] = cz;
    }
    if (it == NPT - 1) break;

    float bestv = -1.f; int besti = p0;
    #pragma unroll
    for (int i = 0; i < PPT; ++i) {
      const float dx = __fsub_rn(px[i], cx);
      const float dy = __fsub_rn(py[i], cy);
      const float dz = __fsub_rn(pz[i], cz);
      const float d = __fadd_rn(__fadd_rn(__fmul_rn(dx, dx), __fmul_rn(dy, dy)),
                                __fmul_rn(dz, dz));
      const float nd = fminf(dist[i], d);
      dist[i] = nd;
      const bool g = nd > bestv;      // strict >: first max wins within thread
      bestv = g ? nd : bestv;
      besti = g ? (p0 + i) : besti;
    }

    // wave-wide max VALUE (distances >= 0, bound_ctrl zero-fill safe)
    float m = bestv;
    m = dpp_max_step<0x111>(m);   // row_shr:1
    m = dpp_max_step<0x112>(m);   // row_shr:2
    m = dpp_max_step<0x114>(m);   // row_shr:4
    m = dpp_max_step<0x118>(m);   // row_shr:8
    m = dpp_max_step<0x142>(m);   // row_bcast:15
    m = dpp_max_step<0x143>(m);   // row_bcast:31  -> lane 63 holds wave max
    const float wmax =
        __int_as_float(__builtin_amdgcn_readlane(__float_as_int(m), 63));

    // lowest lane matching wave max == lowest index in wave
    const unsigned long long mask = __ballot(bestv == wmax);
    const int wl = __ffsll((long long)mask) - 1;
    const int widx = __builtin_amdgcn_readlane(besti, wl);

    const int buf = it & 1;
    if ((tid & 63) == 0)
      sl[buf][wave] = make_uint2(__float_as_uint(wmax), (unsigned)widx);
    __syncthreads();   // single barrier; double-buffered slots prevent WAR

    // all threads combine the 4 wave winners (2x ds_read_b128 broadcast)
    const uint4* p4 = (const uint4*)&sl[buf][0];
    const uint4 q0 = p4[0], q1 = p4[1];
    float bv; int bi;
    {
      bv = __uint_as_float(q0.x); bi = (int)q0.y;
      const float v1 = __uint_as_float(q0.z);
      if (v1 > bv) { bv = v1; bi = (int)q0.w; }
      const float v2 = __uint_as_float(q1.x);
      if (v2 > bv) { bv = v2; bi = (int)q1.y; }
      const float v3 = __uint_as_float(q1.z);
      if (v3 > bv) { bv = v3; bi = (int)q1.w; }
    }
    cur = bi;
  }

  __syncthreads();
  float* outb = out_newxyz + (size_t)b * NPT * 3;
  for (int i = tid; i < NPT * 3 / 4; i += FPS_T)
    *(float4*)&outb[4 * i] = *(const float4*)&olds[4 * i];
}

// ---------------------------------------------------------------------------
// Kernel 3: layer-1 MFMA matmul with fused ball query (unchanged from r12).
// ---------------------------------------------------------------------------
__global__ __launch_bounds__(256) void mm1_mfma_kernel(
    const float* __restrict__ xyz, const unsigned short* __restrict__ pointsb,
    const float* __restrict__ newxyz, const unsigned short* __restrict__ Wb,
    unsigned short* __restrict__ Y, float* __restrict__ psum,
    float* __restrict__ psq) {
  constexpr int KP = 104;
  __shared__ __align__(16) unsigned short As[64 * KP];
  __shared__ __align__(16) unsigned short ly[64 * 64];
  __shared__ float ssum[64], ssq[64];
  __shared__ int   gidxL[64];
  __shared__ float cents[8];
  const int tid = threadIdx.x, bid = blockIdx.x;
  const int wave = tid >> 6, lane = tid & 63;
  const size_t r0 = (size_t)bid * 64;
  const int b = (bid * 2) >> 10;

  // ---- fused ball query: wave w in {0,1} handles group bid*2+w ----
  if (wave < 2) {
    const int gs = bid * 2 + wave;
    const float* base = xyz + (size_t)b * NPTS * 3;
    const float* c = newxyz + (size_t)gs * 3;
    const float cx = c[0], cy = c[1], cz = c[2];
    if (lane == 0) {
      cents[wave * 4 + 0] = cx;
      cents[wave * 4 + 1] = cy;
      cents[wave * 4 + 2] = cz;
    }
    const float R2 = (float)(0.2 * 0.2);
    int* g = &gidxL[wave * 32];
    int count = 0;
    int first = -1;
    for (int ch = 0; ch < NPTS / 64; ++ch) {
      const int i = ch * 64 + lane;
      const float dx = __fsub_rn(base[3 * i + 0], cx);
      const float dy = __fsub_rn(base[3 * i + 1], cy);
      const float dz = __fsub_rn(base[3 * i + 2], cz);
      const float d = __fadd_rn(
          __fadd_rn(__fmul_rn(dx, dx), __fmul_rn(dy, dy)), __fmul_rn(dz, dz));
      const bool pred = !(d > R2);
      const unsigned long long mask = __ballot(pred);
      if (mask) {
        if (count == 0) first = ch * 64 + (__ffsll((long long)mask) - 1);
        const int rank = __popcll(mask & ((1ull << lane) - 1ull));
        const int pos = count + rank;
        if (pred && pos < NSAMP) g[pos] = i;
        count += (int)__popcll(mask);
        if (count >= NSAMP) break;
      }
    }
    if (first < 0) first = 0;
    for (int j = count + lane; j < NSAMP; j += 64) g[j] = first;
  }
  if (tid < 64) { ssum[tid] = 0.f; ssq[tid] = 0.f; }
  __syncthreads();

  // ---- gather: 4 threads/row, 16 bf16 channels each (2x uint4 loads) ----
  {
    const int row = tid >> 2, q = tid & 3;
    const int gpt = gidxL[row];
    const unsigned short* pf = pointsb + ((size_t)b * NPTS + gpt) * 64 + 16 * q;
    const uint4 u0 = *(const uint4*)pf;
    const uint4 u1 = *(const uint4*)(pf + 8);
    uint4* dst = (uint4*)&As[row * KP + 16 * q];
    dst[0] = u0; dst[1] = u1;
    if (q == 0) {
      const float* px = xyz + ((size_t)b * NPTS + gpt) * 3;
      const float* pc = &cents[(row >> 5) * 4];
      const float rx = px[0] - pc[0];
      const float ry = px[1] - pc[1];
      const float rz = px[2] - pc[2];
      uint4* d2 = (uint4*)&As[row * KP + 64];
      d2[0] = uint4{cvt_pk_bf16(rx, ry), cvt_pk_bf16(rz, 0.f), 0u, 0u};
      d2[1] = uint4{0u, 0u, 0u, 0u};
      d2[2] = uint4{0u, 0u, 0u, 0u};
      d2[3] = uint4{0u, 0u, 0u, 0u};
    }
  }
  __syncthreads();

  const int l15 = lane & 15, kq = lane >> 4;
  const unsigned short* abase = &As[(wave * 16 + l15) * KP + kq * 8];
  const bfrag a0 = *(const bfrag*)abase;
  const bfrag a1 = *(const bfrag*)(abase + 32);
  const bfrag a2 = *(const bfrag*)(abase + 64);

  #pragma unroll
  for (int nt = 0; nt < 4; ++nt) {
    const unsigned short* wsrc = Wb + (size_t)(nt * 16 + l15) * 96 + kq * 8;
    const bfrag b0 = *(const bfrag*)wsrc;
    const bfrag b1 = *(const bfrag*)(wsrc + 32);
    const bfrag b2 = *(const bfrag*)(wsrc + 64);
    f32x4 acc = {0.f, 0.f, 0.f, 0.f};
    acc = __builtin_amdgcn_mfma_f32_16x16x32_bf16(a0, b0, acc, 0, 0, 0);
    acc = __builtin_amdgcn_mfma_f32_16x16x32_bf16(a1, b1, acc, 0, 0, 0);
    acc = __builtin_amdgcn_mfma_f32_16x16x32_bf16(a2, b2, acc, 0, 0, 0);

    float s = acc[0] + acc[1] + acc[2] + acc[3];
    float q = acc[0]*acc[0] + acc[1]*acc[1] + acc[2]*acc[2] + acc[3]*acc[3];
    s += __shfl_xor(s, 16); q += __shfl_xor(q, 16);
    s += __shfl_xor(s, 32); q += __shfl_xor(q, 32);
    if (kq == 0) {
      atomicAdd(&ssum[nt * 16 + l15], s);
      atomicAdd(&ssq [nt * 16 + l15], q);
    }
    const unsigned p01 = cvt_pk_bf16(acc[0], acc[1]);
    const unsigned p23 = cvt_pk_bf16(acc[2], acc[3]);
    const int colo = nt * 16 + l15;
    const int rbase = wave * 16 + kq * 4;
    ly[(rbase + 0) * 64 + colo] = (unsigned short)(p01 & 0xffffu);
    ly[(rbase + 1) * 64 + colo] = (unsigned short)(p01 >> 16);
    ly[(rbase + 2) * 64 + colo] = (unsigned short)(p23 & 0xffffu);
    ly[(rbase + 3) * 64 + colo] = (unsigned short)(p23 >> 16);
  }
  __syncthreads();
  {
    const uint4* lsrc = (const uint4*)ly;
    uint4* gdst = (uint4*)(Y + r0 * 64);
    #pragma unroll
    for (int i = tid; i < 64 * 64 * 2 / 16; i += 256) gdst[i] = lsrc[i];
  }
  if (tid < 64) {
    psum[(size_t)bid * 64 + tid] = ssum[tid];
    psq [(size_t)bid * 64 + tid] = ssq [tid];
  }
}

// ---------------------------------------------------------------------------
// Layer 2 MFMA (unchanged).
// ---------------------------------------------------------------------------
static __device__ __forceinline__ bfrag affine_relu_frag(
    const unsigned short* __restrict__ src, const float* __restrict__ st,
    int c0) {
  union { bfrag f; unsigned u[4]; } r;
  const uint4 raw = *(const uint4*)src;
  const unsigned w[4] = {raw.x, raw.y, raw.z, raw.w};
  #pragma unroll
  for (int p = 0; p < 4; ++p) {
    const int c = c0 + 2 * p;
    float lo = bf2f((unsigned short)(w[p] & 0xffffu));
    float hi = bf2f((unsigned short)(w[p] >> 16));
    lo = fmaxf(fmaf(lo, st[2 * c + 0], st[2 * c + 1]), 0.f);
    hi = fmaxf(fmaf(hi, st[2 * c + 2], st[2 * c + 3]), 0.f);
    r.u[p] = cvt_pk_bf16(lo, hi);
  }
  return r.f;
}

template <int COUT, int WAVES>
__global__ __launch_bounds__(WAVES * 64) void mm_mfma_kernel(
    const unsigned short* __restrict__ Xin, const unsigned short* __restrict__ Wb,
    const float* __restrict__ stin, unsigned short* __restrict__ Y,
    float* __restrict__ psum, float* __restrict__ psq) {
  constexpr int NT = COUT / 16;
  constexpr int ROWS = WAVES * 16;
  __shared__ float ssum[COUT], ssq[COUT];
  __shared__ __align__(16) unsigned short ly[ROWS * COUT];
  const int tid = threadIdx.x, bid = blockIdx.x;
  const int wave = tid >> 6, lane = tid & 63;
  const int l15 = lane & 15, kq = lane >> 4;
  const size_t r0 = (size_t)bid * ROWS;
  if (tid < COUT) { ssum[tid] = 0.f; ssq[tid] = 0.f; }

  const int arow = wave * 16 + l15;
  const unsigned short* asrc = Xin + (r0 + arow) * 64 + kq * 8;
  const bfrag a0 = affine_relu_frag(asrc, stin, kq * 8);
  const bfrag a1 = affine_relu_frag(asrc + 32, stin, 32 + kq * 8);
  __syncthreads();

  #pragma unroll
  for (int nt = 0; nt < NT; ++nt) {
    const unsigned short* wsrc = Wb + (size_t)(nt * 16 + l15) * 64 + kq * 8;
    const bfrag b0 = *(const bfrag*)wsrc;
    const bfrag b1 = *(const bfrag*)(wsrc + 32);
    f32x4 acc = {0.f, 0.f, 0.f, 0.f};
    acc = __builtin_amdgcn_mfma_f32_16x16x32_bf16(a0, b0, acc, 0, 0, 0);
    acc = __builtin_amdgcn_mfma_f32_16x16x32_bf16(a1, b1, acc, 0, 0, 0);

    float s = acc[0] + acc[1] + acc[2] + acc[3];
    float q = acc[0]*acc[0] + acc[1]*acc[1] + acc[2]*acc[2] + acc[3]*acc[3];
    s += __shfl_xor(s, 16); q += __shfl_xor(q, 16);
    s += __shfl_xor(s, 32); q += __shfl_xor(q, 32);
    if (kq == 0) {
      atomicAdd(&ssum[nt * 16 + l15], s);
      atomicAdd(&ssq [nt * 16 + l15], q);
    }
    const unsigned p01 = cvt_pk_bf16(acc[0], acc[1]);
    const unsigned p23 = cvt_pk_bf16(acc[2], acc[3]);
    const int colo = nt * 16 + l15;
    const int rbase = wave * 16 + kq * 4;
    ly[(rbase + 0) * COUT + colo] = (unsigned short)(p01 & 0xffffu);
    ly[(rbase + 1) * COUT + colo] = (unsigned short)(p01 >> 16);
    ly[(rbase + 2) * COUT + colo] = (unsigned short)(p23 & 0xffffu);
    ly[(rbase + 3) * COUT + colo] = (unsigned short)(p23 >> 16);
  }
  __syncthreads();
  {
    const uint4* lsrc = (const uint4*)ly;
    uint4* gdst = (uint4*)(Y + r0 * COUT);
    #pragma unroll
    for (int i = tid; i < ROWS * COUT * 2 / 16; i += WAVES * 64) gdst[i] = lsrc[i];
  }
  if (tid < COUT) {
    psum[(size_t)bid * COUT + tid] = ssum[tid];
    psq [(size_t)bid * COUT + tid] = ssq [tid];
  }
}

// ---------------------------------------------------------------------------
// Layer 3 MFMA + fused maxpool (unchanged).
// ---------------------------------------------------------------------------
__global__ __launch_bounds__(512) void mm3_pool_kernel(
    const unsigned short* __restrict__ Xin, const unsigned short* __restrict__ Wb,
    const float* __restrict__ stin, float* __restrict__ pooled,
    float* __restrict__ psum, float* __restrict__ psq) {
  constexpr int COUT = 128, NT = 8;
  __shared__ float ssum[COUT], ssq[COUT];
  __shared__ float pm[8][COUT];
  const int tid = threadIdx.x, bid = blockIdx.x;
  const int wave = tid >> 6, lane = tid & 63;
  const int l15 = lane & 15, kq = lane >> 4;
  const size_t r0 = (size_t)bid * 128;
  if (tid < COUT) { ssum[tid] = 0.f; ssq[tid] = 0.f; }

  const int arow = wave * 16 + l15;
  const unsigned short* asrc = Xin + (r0 + arow) * 64 + kq * 8;
  const bfrag a0 = affine_relu_frag(asrc, stin, kq * 8);
  const bfrag a1 = affine_relu_frag(asrc + 32, stin, 32 + kq * 8);
  __syncthreads();

  #pragma unroll
  for (int nt = 0; nt < NT; ++nt) {
    const unsigned short* wsrc = Wb + (size_t)(nt * 16 + l15) * 64 + kq * 8;
    const bfrag b0 = *(const bfrag*)wsrc;
    const bfrag b1 = *(const bfrag*)(wsrc + 32);
    f32x4 acc = {0.f, 0.f, 0.f, 0.f};
    acc = __builtin_amdgcn_mfma_f32_16x16x32_bf16(a0, b0, acc, 0, 0, 0);
    acc = __builtin_amdgcn_mfma_f32_16x16x32_bf16(a1, b1, acc, 0, 0, 0);

    float s = acc[0] + acc[1] + acc[2] + acc[3];
    float q = acc[0]*acc[0] + acc[1]*acc[1] + acc[2]*acc[2] + acc[3]*acc[3];
    s += __shfl_xor(s, 16); q += __shfl_xor(q, 16);
    s += __shfl_xor(s, 32); q += __shfl_xor(q, 32);
    float mx = fmaxf(fmaxf(acc[0], acc[1]), fmaxf(acc[2], acc[3]));
    mx = fmaxf(mx, __shfl_xor(mx, 16));
    mx = fmaxf(mx, __shfl_xor(mx, 32));
    if (kq == 0) {
      atomicAdd(&ssum[nt * 16 + l15], s);
      atomicAdd(&ssq [nt * 16 + l15], q);
      pm[wave][nt * 16 + l15] = mx;
    }
  }
  __syncthreads();
  {
    const int g = tid >> 7, col = tid & 127;
    const float v = fmaxf(pm[2 * g][col], pm[2 * g + 1][col]);
    pooled[(r0 >> 5) * COUT + g * COUT + col] = v;
  }
  if (tid < COUT) {
    psum[(size_t)bid * COUT + tid] = ssum[tid];
    psq [(size_t)bid * COUT + tid] = ssq [tid];
  }
}

// ---------------------------------------------------------------------------
// BN stats finalize (unchanged).
// ---------------------------------------------------------------------------
__global__ __launch_bounds__(256) void finalize_kernel(
    const float* __restrict__ psum, const float* __restrict__ psq,
    const float* __restrict__ gam, const float* __restrict__ bet,
    float* __restrict__ st, int C, int nb) {
  const int c = blockIdx.x, tid = threadIdx.x;
  float s = 0.f, q = 0.f;
  for (int i = tid; i < nb; i += 256) {
    s += psum[(size_t)i * C + c];
    q += psq [(size_t)i * C + c];
  }
  #pragma unroll
  for (int off = 32; off > 0; off >>= 1) {
    s += __shfl_down(s, off);
    q += __shfl_down(q, off);
  }
  __shared__ float as_[4], aq_[4];
  if ((tid & 63) == 0) { as_[tid >> 6] = s; aq_[tid >> 6] = q; }
  __syncthreads();
  if (tid == 0) {
    s = as_[0] + as_[1] + as_[2] + as_[3];
    q = aq_[0] + aq_[1] + aq_[2] + aq_[3];
    const float invM = 1.f / (float)MROWS;
    const float mean = s * invM;
    const float var = q * invM - mean * mean;
    const float inv = 1.f / sqrtf(var + EPSV);
    const float sc = gam[c] * inv;
    st[2 * c + 0] = sc;
    st[2 * c + 1] = bet[c] - mean * sc;
  }
}

// ---------------------------------------------------------------------------
// Epilogue: BN3 affine + relu on the pooled tensor -> new_points.
// ---------------------------------------------------------------------------
__global__ __launch_bounds__(256) void bn_relu_kernel(
    const float* __restrict__ pooled, const float* __restrict__ st,
    float* __restrict__ out) {
  __shared__ float s_st[256];
  const int tid = threadIdx.x;
  s_st[tid] = st[tid];
  __syncthreads();
  const int n4 = NBATCH * NPT * 128 / 4;
  for (int i = blockIdx.x * 256 + tid; i < n4; i += gridDim.x * 256) {
    float4 v = ((const float4*)pooled)[i];
    const int c0 = (i * 4) & 127;
    v.x = fmaxf(fmaf(v.x, s_st[2 * c0 + 0], s_st[2 * c0 + 1]), 0.f);
    v.y = fmaxf(fmaf(v.y, s_st[2 * c0 + 2], s_st[2 * c0 + 3]), 0.f);
    v.z = fmaxf(fmaf(v.z, s_st[2 * c0 + 4], s_st[2 * c0 + 5]), 0.f);
    v.w = fmaxf(fmaf(v.w, s_st[2 * c0 + 6], s_st[2 * c0 + 7]), 0.f);
    ((float4*)out)[i] = v;
  }
}

// ---------------------------------------------------------------------------
extern "C" void kernel_launch(void* const* d_in, const int* in_sizes, int n_in,
                              void* d_out, int out_size, void* d_ws, size_t ws_size,
                              hipStream_t stream) {
  (void)in_sizes; (void)n_in; (void)out_size; (void)ws_size;
  const float* xyz    = (const float*)d_in[0];
  const float* points = (const float*)d_in[1];
  const float* w0 = (const float*)d_in[2];
  const float* g0 = (const float*)d_in[4];
  const float* be0 = (const float*)d_in[5];
  const float* w1 = (const float*)d_in[6];
  const float* g1 = (const float*)d_in[8];
  const float* be1 = (const float*)d_in[9];
  const float* w2 = (const float*)d_in[10];
  const float* g2 = (const float*)d_in[12];
  const float* be2 = (const float*)d_in[13];

  float* out = (float*)d_out;
  float* newxyz = out;
  float* newpts = out + (size_t)NBATCH * NPT * 3;

  char* ws = (char*)d_ws;
  // [0,67MB)      Y1 (dead after mm2) / P3 pooled 8MB (written by mm3 later)
  // [67,75.4MB)   pointsb (bf16 points, 8.4MB)
  // [134,201MB)   Y2
  unsigned short* Y1 = (unsigned short*)ws;
  float* P3 = (float*)ws;
  unsigned short* pointsb = (unsigned short*)(ws + 67108864);
  unsigned short* Y2 = (unsigned short*)(ws + 134217728);
  float* psum = (float*)(ws + 203423744);
  float* psq  = (float*)(ws + 205520896);
  float* st   = (float*)(ws + 207618048);
  float* st1 = st, *st2 = st + 256, *st3 = st + 512;
  unsigned short* wb0 = (unsigned short*)(ws + 207621120);
  unsigned short* wb1 = (unsigned short*)(ws + 207621120 + 12288);
  unsigned short* wb2 = (unsigned short*)(ws + 207621120 + 12288 + 8192);

  prep_kernel<<<512, 256, 0, stream>>>(w0, w1, w2, wb0, wb1, wb2, points, pointsb);
  fps_kernel<<<NBATCH, FPS_T, 0, stream>>>(xyz, newxyz);
  mm1_mfma_kernel<<<MROWS / 64, 256, 0, stream>>>(xyz, pointsb, newxyz, wb0, Y1, psum, psq);
  finalize_kernel<<<64, 256, 0, stream>>>(psum, psq, g0, be0, st1, 64, MROWS / 64);
  mm_mfma_kernel<64, 4><<<MROWS / 64, 256, 0, stream>>>(Y1, wb1, st1, Y2, psum, psq);
  finalize_kernel<<<64, 256, 0, stream>>>(psum, psq, g1, be1, st2, 64, MROWS / 64);
  mm3_pool_kernel<<<MROWS / 128, 512, 0, stream>>>(Y2, wb2, st2, P3, psum, psq);
  finalize_kernel<<<128, 256, 0, stream>>>(psum, psq, g2, be2, st3, 128, MROWS / 128);
  bn_relu_kernel<<<2048, 256, 0, stream>>>(P3, st3, newpts);
}